// Round 11
// baseline (532.963 us; speedup 1.0000x reference)
//
#include <hip/hip_runtime.h>

// ---------------------------------------------------------------------------
// AttentionBlock (SD-style). Round 11:
//  - R10 (best, 533 µs) + extend the verified launch_bounds occupancy hint
//    to the whole MFMA family, sized by register arithmetic:
//      bgemm MT=64 -> (256,4)   [acc 32 regs, cap 128]
//      bgemm MT=128 -> (256,3)  [acc 64 regs, cap ~170, m97-family]
//      cross_gemms -> (256,2)   [acc 128 regs, cap 256]
//      mattn -> (256,3)         [LDS-capped at 3 blocks/CU anyway]
//    (R10 evidence: same hint on geglu: VGPR 76->56, occ 29->35%, 103->82 µs.)
//  - R8 crash root-caused to merged prep_k (retired); preps stay separate.
// B=8, C=640, HW=1024, H=8, DH=80, CTX 77x512.
// ---------------------------------------------------------------------------

#define DH 80

typedef __attribute__((ext_vector_type(8))) short bf16x8;
typedef __attribute__((ext_vector_type(4))) float floatx4;

static __device__ __forceinline__ float gelu_f(float x) {
    return 0.5f * x * (1.0f + erff(x * 0.70710678118654752f));
}
static __device__ __forceinline__ unsigned short f2bf(float f) {
    unsigned u = __float_as_uint(f);
    u = (u + 0x7fffu + ((u >> 16) & 1u)) >> 16;
    return (unsigned short)u;
}
static __device__ __forceinline__ float bf2f(unsigned short s) {
    return __uint_as_float(((unsigned)s) << 16);
}
static __device__ __forceinline__ void async_copy16(const void* g, void* l) {
    __builtin_amdgcn_global_load_lds(
        (const __attribute__((address_space(1))) unsigned int*)g,
        (__attribute__((address_space(3))) unsigned int*)l, 16, 0, 0);
}

// ------------------------- GroupNorm stats ---------------------------------
__global__ __launch_bounds__(256) void gn_stats_k(const float* __restrict__ x,
                                                  float* __restrict__ stats) {
    const int ng = blockIdx.x;                       // n*32 + g
    const float4* base = (const float4*)(x + (size_t)ng * 20480);
    float s = 0.f, s2 = 0.f;
    for (int i = threadIdx.x; i < 5120; i += 256) {
        float4 v = base[i];
        s  += v.x + v.y + v.z + v.w;
        s2 += v.x*v.x + v.y*v.y + v.z*v.z + v.w*v.w;
    }
    for (int m = 1; m < 64; m <<= 1) { s += __shfl_xor(s, m); s2 += __shfl_xor(s2, m); }
    __shared__ float rs[4], rs2[4];
    if ((threadIdx.x & 63) == 0) { rs[threadIdx.x >> 6] = s; rs2[threadIdx.x >> 6] = s2; }
    __syncthreads();
    if (threadIdx.x == 0) {
        float ts = rs[0] + rs[1] + rs[2] + rs[3];
        float t2 = rs2[0] + rs2[1] + rs2[2] + rs2[3];
        float mu = ts * (1.f / 20480.f);
        float var = t2 * (1.f / 20480.f) - mu * mu;
        stats[ng * 2]     = mu;
        stats[ng * 2 + 1] = rsqrtf(var + 1e-6f);
    }
}

// ----------------- GroupNorm apply + transpose, bf16 out --------------------
__global__ __launch_bounds__(256) void gn_apply_t_k(const float* __restrict__ x,
                                                    const float* __restrict__ stats,
                                                    const float* __restrict__ gs,
                                                    const float* __restrict__ gb,
                                                    unsigned short* __restrict__ out) {
    const int p0 = blockIdx.x * 32, c0 = blockIdx.y * 32, n = blockIdx.z;
    __shared__ float tile[32][33];
    const int t = threadIdx.x;
    {
        const int cl = t >> 5, pl = t & 31;
#pragma unroll
        for (int i = 0; i < 4; ++i) {
            int c = c0 + cl + i * 8;
            int g = c / 20;
            float mu = stats[(n * 32 + g) * 2];
            float rstd = stats[(n * 32 + g) * 2 + 1];
            float v = x[(size_t)n * 655360 + (size_t)c * 1024 + p0 + pl];
            tile[cl + i * 8][pl] = (v - mu) * rstd * gs[c] + gb[c];
        }
    }
    __syncthreads();
    {
        const int pl = t >> 5, cl = t & 31;
#pragma unroll
        for (int i = 0; i < 4; ++i) {
            int p = p0 + pl + i * 8;
            out[((size_t)n * 1024 + p) * 640 + c0 + cl] = f2bf(tile[cl][pl + i * 8]);
        }
    }
}

// --------------------- LayerNorm (bf16 in, bf16 out) ------------------------
__global__ __launch_bounds__(256) void ln_k(const unsigned short* __restrict__ x,
                                            const float* __restrict__ g,
                                            const float* __restrict__ b,
                                            unsigned short* __restrict__ o) {
    const int row = blockIdx.x * 4 + (threadIdx.x >> 6);
    const int lane = threadIdx.x & 63;
    const unsigned short* xr = x + (size_t)row * 640;
    float v[10];
    float s = 0.f, s2 = 0.f;
#pragma unroll
    for (int i = 0; i < 10; ++i) {
        v[i] = bf2f(xr[lane + i * 64]);
        s += v[i]; s2 += v[i] * v[i];
    }
    for (int m = 1; m < 64; m <<= 1) { s += __shfl_xor(s, m); s2 += __shfl_xor(s2, m); }
    float mu = s * (1.f / 640.f);
    float var = s2 * (1.f / 640.f) - mu * mu;
    float r = rsqrtf(var + 1e-5f);
    unsigned short* orow = o + (size_t)row * 640;
#pragma unroll
    for (int i = 0; i < 10; ++i) {
        int c = lane + i * 64;
        orow[c] = f2bf((v[i] - mu) * r * g[c] + b[c]);
    }
}

// ---------------- merged weight prep: all [K][N]->[N][K] transposes ---------
__global__ __launch_bounds__(256) void prep_tr_k(
        const float* __restrict__ sa_in_w,  unsigned short* __restrict__ sa_in_wb,
        const float* __restrict__ sa_out_w, unsigned short* __restrict__ sa_out_wb,
        const float* __restrict__ ca_q_w,   unsigned short* __restrict__ ca_q_wb,
        const float* __restrict__ ca_k_w,   unsigned short* __restrict__ ca_k_wb,
        const float* __restrict__ ca_v_w,   unsigned short* __restrict__ ca_v_wb,
        const float* __restrict__ ca_out_w, unsigned short* __restrict__ ca_out_wb,
        const float* __restrict__ lin1_w,   unsigned short* __restrict__ lin1_wb,
        const float* __restrict__ lin2_w,   unsigned short* __restrict__ lin2_wb) {
    const int bid = blockIdx.x;
    int r; const float* W; unsigned short* O; int K, N;
    if (bid < 1200)      { r = bid;        W = sa_in_w;  O = sa_in_wb;  K = 640;  N = 1920; }
    else if (bid < 1600) { r = bid - 1200; W = sa_out_w; O = sa_out_wb; K = 640;  N = 640;  }
    else if (bid < 2000) { r = bid - 1600; W = ca_q_w;   O = ca_q_wb;   K = 640;  N = 640;  }
    else if (bid < 2320) { r = bid - 2000; W = ca_k_w;   O = ca_k_wb;   K = 512;  N = 640;  }
    else if (bid < 2640) { r = bid - 2320; W = ca_v_w;   O = ca_v_wb;   K = 512;  N = 640;  }
    else if (bid < 3040) { r = bid - 2640; W = ca_out_w; O = ca_out_wb; K = 640;  N = 640;  }
    else if (bid < 6240) { r = bid - 3040; W = lin1_w;   O = lin1_wb;   K = 640;  N = 5120; }
    else                 { r = bid - 6240; W = lin2_w;   O = lin2_wb;   K = 2560; N = 640;  }
    const int tX = K >> 5;
    const int k0 = (r % tX) * 32, n0 = (r / tX) * 32;
    __shared__ float tile[32][33];
    const int tr = threadIdx.x >> 5, tc = threadIdx.x & 31;
#pragma unroll
    for (int i = 0; i < 4; ++i)
        tile[tr + i * 8][tc] = W[(size_t)(k0 + tr + i * 8) * N + n0 + tc];
    __syncthreads();
#pragma unroll
    for (int i = 0; i < 4; ++i)
        O[(size_t)(n0 + tr + i * 8) * K + k0 + tc] = f2bf(tile[tc][tr + i * 8]);
}

// ------- merged elementwise prep: conv1/co cvt, ctx pad-cvt, zero vT_c ------
__global__ __launch_bounds__(256) void prep_ew_k(const float* __restrict__ w1,
                                                 unsigned short* __restrict__ c1,
                                                 const float* __restrict__ w2,
                                                 unsigned short* __restrict__ c2,
                                                 const float* __restrict__ ctx,
                                                 unsigned short* __restrict__ cb,
                                                 unsigned int* __restrict__ vtc) {
    const int i = blockIdx.x * 256 + threadIdx.x;
    if (i < 409600) c1[i] = f2bf(w1[i]);
    else if (i < 819200) c2[i - 409600] = f2bf(w2[i - 409600]);
    else if (i < 1146880) {
        const int j = i - 819200;
        const int r = j >> 9;
        cb[j] = (r < 616) ? f2bf(ctx[j]) : (unsigned short)0;
    } else {
        vtc[i - 1146880] = 0u;   // zero cross V^T (masked cols read by attn)
    }
}

// --------------------------- bf16 MFMA GEMM ---------------------------------
// C[M,N] = A[M,K] * B^T[N,K] (+bias, epilogue). MT in {128, 64}.
enum { EPI_OUT = 0, EPI_RES = 1, EPI_CONVT = 3, EPI_QKV = 5 };

template <int EPI, typename CT, int MT>
__global__ __launch_bounds__(256, MT == 128 ? 3 : 4)
void bgemm_k(const unsigned short* __restrict__ A, int lda,
             const unsigned short* __restrict__ B, int ldb,
             const float* __restrict__ bias,
             CT* __restrict__ C, int ldc,
             const float* __restrict__ aux,
             unsigned short* __restrict__ extra,
             int M, int N, int K) {
    constexpr int MI = MT / 32;   // m-fragments per wave (4 or 2)
    __shared__ __attribute__((aligned(16))) short As[MT * 32];
    __shared__ __attribute__((aligned(16))) short Bs[128 * 32];
    const int t = threadIdx.x;
    const int lane = t & 63;
    const int w = __builtin_amdgcn_readfirstlane(t >> 6);
    const int m0 = blockIdx.x * MT, n0 = blockIdx.y * 128;
    const int wm = (MT == 128) ? (w >> 1) * 64 : (w & 1) * 32;
    const int wn = (MT == 128) ? (w & 1) * 64 : (w >> 1) * 64;

    const int sr = lane >> 2;
    const int sc = (lane & 3) * 8;
    const int fm = lane & 15;
    const int fq = (lane >> 4) * 8;

    floatx4 acc[MI][4];
#pragma unroll
    for (int i = 0; i < MI; ++i)
#pragma unroll
        for (int j = 0; j < 4; ++j) acc[i][j] = (floatx4){0.f, 0.f, 0.f, 0.f};

    for (int k0 = 0; k0 < K; k0 += 32) {
        const unsigned short* a0 = A + (size_t)(m0 + w * 16 + sr) * lda + k0 + sc;
        const unsigned short* b0 = B + (size_t)(n0 + w * 16 + sr) * ldb + k0 + sc;
        async_copy16(a0, As + (w * 16) * 32);
        if constexpr (MT == 128)
            async_copy16(a0 + (size_t)64 * lda, As + (64 + w * 16) * 32);
        async_copy16(b0,                    Bs + (w * 16) * 32);
        async_copy16(b0 + (size_t)64 * ldb, Bs + (64 + w * 16) * 32);
        __syncthreads();
        bf16x8 af[MI], bfr[4];
#pragma unroll
        for (int i = 0; i < MI; ++i)
            af[i]  = *(const bf16x8*)(As + (wm + i * 16 + fm) * 32 + fq);
#pragma unroll
        for (int j = 0; j < 4; ++j)
            bfr[j] = *(const bf16x8*)(Bs + (wn + j * 16 + fm) * 32 + fq);
#pragma unroll
        for (int i = 0; i < MI; ++i)
#pragma unroll
            for (int j = 0; j < 4; ++j)
                acc[i][j] = __builtin_amdgcn_mfma_f32_16x16x32_bf16(af[i], bfr[j], acc[i][j], 0, 0, 0);
        __syncthreads();
    }

    float bv[4];
#pragma unroll
    for (int j = 0; j < 4; ++j) bv[j] = bias ? bias[n0 + wn + j * 16 + fm] : 0.f;
    const int rbase = (lane >> 4) * 4;

#pragma unroll
    for (int i = 0; i < MI; ++i) {
#pragma unroll
        for (int j = 0; j < 4; ++j) {
            const int n = n0 + wn + j * 16 + fm;
#pragma unroll
            for (int r = 0; r < 4; ++r) {
                const int m = m0 + wm + i * 16 + rbase + r;
                float v = acc[i][j][r] + bv[j];
                if constexpr (EPI == EPI_OUT) {
                    if constexpr (__is_same(CT, float)) {
                        C[(size_t)m * ldc + n] = v;
                    } else {
                        C[(size_t)m * ldc + n] = f2bf(v);
                    }
                } else if constexpr (EPI == EPI_RES) {
                    const size_t idx = (size_t)m * ldc + n;
                    if constexpr (__is_same(CT, float)) {
                        C[idx] += v;
                    } else {
                        C[idx] = f2bf(bf2f(C[idx]) + v);  // bf16 residual RMW
                    }
                } else if constexpr (EPI == EPI_CONVT) {
                    const int bch = m >> 10, p = m & 1023;
                    const size_t idx = (size_t)bch * 655360 + (size_t)n * 1024 + p;
                    C[idx] = v + aux[idx];
                } else {  // EPI_QKV: n<1280 -> qk store; else V^T scatter
                    if (n < 1280) {
                        C[(size_t)m * 1280 + n] = f2bf(v);
                    } else {
                        const int nv2 = n - 1280;
                        const int hh = nv2 / 80, d = nv2 - hh * 80;
                        const int bb = m >> 10, s = m & 1023;
                        extra[((size_t)(bb * 8 + hh) * 80 + d) * 1024 + s] = f2bf(v);
                    }
                }
            }
        }
    }
}

// -------- cross-attn projections: q (8192x640) + K,V (640x640) in one -------
__global__ __launch_bounds__(256, 2) void cross_gemms_k(
        const unsigned short* __restrict__ xq, const unsigned short* __restrict__ ctx_b,
        const unsigned short* __restrict__ Wq, const unsigned short* __restrict__ Wk,
        const unsigned short* __restrict__ Wv,
        unsigned short* __restrict__ q_out, unsigned short* __restrict__ k_out,
        unsigned short* __restrict__ vT_out) {
    __shared__ __attribute__((aligned(16))) short As[128 * 32];
    __shared__ __attribute__((aligned(16))) short Bs[128 * 32];
    const int bx = blockIdx.x;
    int job, m0, n0, lda, K;
    const unsigned short *A, *B;
    if (bx < 320)      { job = 0; m0 = (bx & 63) * 128; n0 = (bx >> 6) * 128; A = xq;    B = Wq; lda = 640; K = 640; }
    else if (bx < 345) { int i = bx - 320; job = 1; m0 = (i % 5) * 128; n0 = (i / 5) * 128; A = ctx_b; B = Wk; lda = 512; K = 512; }
    else               { int i = bx - 345; job = 2; m0 = (i % 5) * 128; n0 = (i / 5) * 128; A = ctx_b; B = Wv; lda = 512; K = 512; }

    const int t = threadIdx.x;
    const int lane = t & 63;
    const int w = __builtin_amdgcn_readfirstlane(t >> 6);
    const int wm = (w >> 1) * 64, wn = (w & 1) * 64;
    const int sr = lane >> 2, sc = (lane & 3) * 8;
    const int fm = lane & 15, fq = (lane >> 4) * 8;

    floatx4 acc[4][4];
#pragma unroll
    for (int i = 0; i < 4; ++i)
#pragma unroll
        for (int j = 0; j < 4; ++j) acc[i][j] = (floatx4){0.f, 0.f, 0.f, 0.f};

    for (int k0 = 0; k0 < K; k0 += 32) {
        const unsigned short* a0 = A + (size_t)(m0 + w * 16 + sr) * lda + k0 + sc;
        const unsigned short* b0 = B + (size_t)(n0 + w * 16 + sr) * lda + k0 + sc;
        async_copy16(a0,                    As + (w * 16) * 32);
        async_copy16(a0 + (size_t)64 * lda, As + (64 + w * 16) * 32);
        async_copy16(b0,                    Bs + (w * 16) * 32);
        async_copy16(b0 + (size_t)64 * lda, Bs + (64 + w * 16) * 32);
        __syncthreads();
        bf16x8 af[4], bfr[4];
#pragma unroll
        for (int i = 0; i < 4; ++i) {
            af[i]  = *(const bf16x8*)(As + (wm + i * 16 + fm) * 32 + fq);
            bfr[i] = *(const bf16x8*)(Bs + (wn + i * 16 + fm) * 32 + fq);
        }
#pragma unroll
        for (int i = 0; i < 4; ++i)
#pragma unroll
            for (int j = 0; j < 4; ++j)
                acc[i][j] = __builtin_amdgcn_mfma_f32_16x16x32_bf16(af[i], bfr[j], acc[i][j], 0, 0, 0);
        __syncthreads();
    }

    const int rbase = (lane >> 4) * 4;
#pragma unroll
    for (int i = 0; i < 4; ++i) {
#pragma unroll
        for (int j = 0; j < 4; ++j) {
            const int n = n0 + wn + j * 16 + fm;
#pragma unroll
            for (int r = 0; r < 4; ++r) {
                const int m = m0 + wm + i * 16 + rbase + r;
                const float v = acc[i][j][r];
                if (job == 0) {
                    q_out[(size_t)m * 640 + n] = f2bf(v);
                } else if (job == 1) {
                    k_out[(size_t)m * 640 + n] = f2bf(v);
                } else {
                    if (m < 616) {
                        const int bb = m / 77, s = m - bb * 77;
                        const int hh = n / 80, d = n - hh * 80;
                        vT_out[((size_t)(bb * 8 + hh) * 80 + d) * 128 + s] = f2bf(v);
                    }
                }
            }
        }
    }
}

// ---------------- fused GeGLU lin1: h = a * gelu(gate), dual-B GEMM ---------
// 128-M x 64-N dual tile; 0.5 LDS reads/MFMA; LDS 16 KB; 3-blocks/CU hint
// (R10 verified: VGPR 76->56, occ 29->35%, 103->82 µs).
__global__ __launch_bounds__(256, 3) void geglu_k(const unsigned short* __restrict__ A,
                                                  const unsigned short* __restrict__ B1,
                                                  const unsigned short* __restrict__ B2,
                                                  const float* __restrict__ bias,  // [5120]
                                                  unsigned short* __restrict__ H) {
    __shared__ __attribute__((aligned(16))) short As[128 * 32];
    __shared__ __attribute__((aligned(16))) short B1s[64 * 32];
    __shared__ __attribute__((aligned(16))) short B2s[64 * 32];
    const int t = threadIdx.x;
    const int lane = t & 63;
    const int w = __builtin_amdgcn_readfirstlane(t >> 6);
    const int m0 = blockIdx.x * 128, n0 = blockIdx.y * 64;
    const int wm = (w & 1) * 64, wn = (w >> 1) * 32;
    const int sr = lane >> 2, sc = (lane & 3) * 8;
    const int fm = lane & 15, fq = (lane >> 4) * 8;

    floatx4 aa[4][2], ag[4][2];
#pragma unroll
    for (int i = 0; i < 4; ++i)
#pragma unroll
        for (int j = 0; j < 2; ++j) {
            aa[i][j] = (floatx4){0.f, 0.f, 0.f, 0.f};
            ag[i][j] = (floatx4){0.f, 0.f, 0.f, 0.f};
        }

    for (int k0 = 0; k0 < 640; k0 += 32) {
        const unsigned short* a0 = A  + (size_t)(m0 + w * 16 + sr) * 640 + k0 + sc;
        const unsigned short* b1 = B1 + (size_t)(n0 + w * 16 + sr) * 640 + k0 + sc;
        const unsigned short* b2 = B2 + (size_t)(n0 + w * 16 + sr) * 640 + k0 + sc;
        async_copy16(a0,                    As  + (w * 16) * 32);
        async_copy16(a0 + (size_t)64 * 640, As  + (64 + w * 16) * 32);
        async_copy16(b1,                    B1s + (w * 16) * 32);
        async_copy16(b2,                    B2s + (w * 16) * 32);
        __syncthreads();
        bf16x8 af[4], b1f[2], b2f[2];
#pragma unroll
        for (int i = 0; i < 4; ++i)
            af[i]  = *(const bf16x8*)(As  + (wm + i * 16 + fm) * 32 + fq);
#pragma unroll
        for (int j = 0; j < 2; ++j) {
            b1f[j] = *(const bf16x8*)(B1s + (wn + j * 16 + fm) * 32 + fq);
            b2f[j] = *(const bf16x8*)(B2s + (wn + j * 16 + fm) * 32 + fq);
        }
#pragma unroll
        for (int i = 0; i < 4; ++i)
#pragma unroll
            for (int j = 0; j < 2; ++j) {
                aa[i][j] = __builtin_amdgcn_mfma_f32_16x16x32_bf16(af[i], b1f[j], aa[i][j], 0, 0, 0);
                ag[i][j] = __builtin_amdgcn_mfma_f32_16x16x32_bf16(af[i], b2f[j], ag[i][j], 0, 0, 0);
            }
        __syncthreads();
    }

    float bv1[2], bv2[2];
#pragma unroll
    for (int j = 0; j < 2; ++j) {
        bv1[j] = bias[n0 + wn + j * 16 + fm];
        bv2[j] = bias[2560 + n0 + wn + j * 16 + fm];
    }
    const int rbase = (lane >> 4) * 4;
#pragma unroll
    for (int i = 0; i < 4; ++i)
#pragma unroll
        for (int j = 0; j < 2; ++j) {
            const int n = n0 + wn + j * 16 + fm;
#pragma unroll
            for (int r = 0; r < 4; ++r) {
                const int m = m0 + wm + i * 16 + rbase + r;
                const float a = aa[i][j][r] + bv1[j];
                const float g = ag[i][j][r] + bv2[j];
                H[(size_t)m * 2560 + n] = f2bf(a * gelu_f(g));
            }
        }
}

// -------------------- MFMA flash attention (S^T, 2 q-tiles/wave) ------------
__global__ __launch_bounds__(256, 3) void mattn_k(const unsigned short* __restrict__ Qp, int qstride,
                                                  const unsigned short* __restrict__ Kp, int kstride,
                                                  const unsigned short* __restrict__ Vt, int spad,
                                                  unsigned short* __restrict__ Op, int ostride,
                                                  int sq, int sk, float scale) {
    __shared__ __attribute__((aligned(16))) short Ks[64 * 104];   // [64 k][96+8]
    __shared__ __attribute__((aligned(16))) short Vs[80 * 72];    // [80 d][64+8]
    __shared__ __attribute__((aligned(16))) short Ps[128 * 72];   // [128 q][64+8]

    const int t = threadIdx.x;
    const int lane = t & 63;
    const int w = t >> 6;
    const int fm = lane & 15;
    const int quad = lane >> 4;
    const int b = blockIdx.z, h = blockIdx.y;
    const int q0 = blockIdx.x * 128;
    const int qw = q0 + w * 32;            // wave's first q row

    const bf16x8 z8 = {0, 0, 0, 0, 0, 0, 0, 0};
    bf16x8 qf[2][3];
#pragma unroll
    for (int tt = 0; tt < 2; ++tt) {
        const unsigned short* qbase =
            Qp + (size_t)(b * sq + qw + tt * 16 + fm) * qstride + h * DH;
        qf[tt][0] = *(const bf16x8*)(qbase + quad * 8);
        qf[tt][1] = *(const bf16x8*)(qbase + 32 + quad * 8);
        qf[tt][2] = (quad < 2) ? *(const bf16x8*)(qbase + 64 + quad * 8) : z8;
    }

    const unsigned short* kgb = Kp + (size_t)(b * sk) * kstride + h * DH;
    const unsigned short* vgb = Vt + (size_t)((b * 8 + h) * 80) * spad;

    float mrow[2] = {-1e30f, -1e30f}, lrow[2] = {0.f, 0.f};
    floatx4 oacc[2][5];
#pragma unroll
    for (int tt = 0; tt < 2; ++tt)
#pragma unroll
        for (int d = 0; d < 5; ++d) oacc[tt][d] = (floatx4){0.f, 0.f, 0.f, 0.f};

    const int nkt = (sk + 63) >> 6;
    for (int kt = 0; kt < nkt; ++kt) {
        __syncthreads();
        {
            const int tr = t >> 2, tc = t & 3;
            const int kr = kt * 64 + tr;
            const bool ok = kr < sk;
            const unsigned short* krow = kgb + (size_t)kr * kstride;
#pragma unroll
            for (int i = 0; i < 5; ++i) {
                const int col = tc * 4 + i * 16;
                ushort4 v = make_ushort4(0, 0, 0, 0);
                if (ok) v = *(const ushort4*)(krow + col);
                *(ushort4*)(Ks + tr * 104 + col) = v;
            }
            *(ushort4*)(Ks + tr * 104 + 80 + tc * 4) = make_ushort4(0, 0, 0, 0);
        }
#pragma unroll
        for (int i = 0; i < 5; ++i) {
            const int lin = t + i * 256;
            const int row = lin >> 4;
            const int colq = (lin & 15) * 4;
            *(ushort4*)(Vs + row * 72 + colq) =
                *(const ushort4*)(vgb + (size_t)row * spad + kt * 64 + colq);
        }
        __syncthreads();

        floatx4 sacc[2][4];
#pragma unroll
        for (int tt = 0; tt < 2; ++tt)
#pragma unroll
            for (int j = 0; j < 4; ++j) sacc[tt][j] = (floatx4){0.f, 0.f, 0.f, 0.f};
#pragma unroll
        for (int c = 0; c < 3; ++c) {
#pragma unroll
            for (int j = 0; j < 4; ++j) {
                bf16x8 kf = *(const bf16x8*)(Ks + (j * 16 + fm) * 104 + c * 32 + quad * 8);
                sacc[0][j] = __builtin_amdgcn_mfma_f32_16x16x32_bf16(kf, qf[0][c], sacc[0][j], 0, 0, 0);
                sacc[1][j] = __builtin_amdgcn_mfma_f32_16x16x32_bf16(kf, qf[1][c], sacc[1][j], 0, 0, 0);
            }
        }

#pragma unroll
        for (int tt = 0; tt < 2; ++tt) {
            float p[4][4];
#pragma unroll
            for (int j = 0; j < 4; ++j)
#pragma unroll
                for (int r = 0; r < 4; ++r) {
                    const int kk = kt * 64 + j * 16 + quad * 4 + r;
                    p[j][r] = (kk >= sk) ? -1e30f : sacc[tt][j][r] * scale;
                }
            float mx = p[0][0];
#pragma unroll
            for (int j = 0; j < 4; ++j)
#pragma unroll
                for (int r = 0; r < 4; ++r) mx = fmaxf(mx, p[j][r]);
            mx = fmaxf(mx, __shfl_xor(mx, 16));
            mx = fmaxf(mx, __shfl_xor(mx, 32));
            const float mn = fmaxf(mrow[tt], mx);
            const float alpha = __expf(mrow[tt] - mn);
            float rs = 0.f;
#pragma unroll
            for (int j = 0; j < 4; ++j)
#pragma unroll
                for (int r = 0; r < 4; ++r) { p[j][r] = __expf(p[j][r] - mn); rs += p[j][r]; }
            rs += __shfl_xor(rs, 16);
            rs += __shfl_xor(rs, 32);
            lrow[tt] = lrow[tt] * alpha + rs;
            mrow[tt] = mn;

            float al[4];
#pragma unroll
            for (int r = 0; r < 4; ++r) al[r] = __shfl(alpha, quad * 4 + r);
#pragma unroll
            for (int d = 0; d < 5; ++d)
#pragma unroll
                for (int r = 0; r < 4; ++r) oacc[tt][d][r] *= al[r];

#pragma unroll
            for (int j = 0; j < 4; ++j) {
                ushort4 pk;
                pk.x = f2bf(p[j][0]); pk.y = f2bf(p[j][1]);
                pk.z = f2bf(p[j][2]); pk.w = f2bf(p[j][3]);
                *(ushort4*)(Ps + (w * 32 + tt * 16 + fm) * 72 + j * 16 + quad * 4) = pk;
            }
        }
        __syncthreads();

        bf16x8 pf[2][2];
#pragma unroll
        for (int tt = 0; tt < 2; ++tt) {
            pf[tt][0] = *(const bf16x8*)(Ps + (w * 32 + tt * 16 + fm) * 72 + quad * 8);
            pf[tt][1] = *(const bf16x8*)(Ps + (w * 32 + tt * 16 + fm) * 72 + 32 + quad * 8);
        }
#pragma unroll
        for (int d = 0; d < 5; ++d) {
            bf16x8 vf0 = *(const bf16x8*)(Vs + (d * 16 + fm) * 72 + quad * 8);
            bf16x8 vf1 = *(const bf16x8*)(Vs + (d * 16 + fm) * 72 + 32 + quad * 8);
#pragma unroll
            for (int tt = 0; tt < 2; ++tt) {
                oacc[tt][d] = __builtin_amdgcn_mfma_f32_16x16x32_bf16(pf[tt][0], vf0, oacc[tt][d], 0, 0, 0);
                oacc[tt][d] = __builtin_amdgcn_mfma_f32_16x16x32_bf16(pf[tt][1], vf1, oacc[tt][d], 0, 0, 0);
            }
        }
    }

#pragma unroll
    for (int tt = 0; tt < 2; ++tt) {
        unsigned short* obase = Op + (size_t)(b * sq + qw + tt * 16) * ostride + h * DH;
#pragma unroll
        for (int r = 0; r < 4; ++r) {
            const float lr = __shfl(lrow[tt], quad * 4 + r);
            const float inv = 1.f / lr;
#pragma unroll
            for (int d = 0; d < 5; ++d)
                obase[(size_t)(quad * 4 + r) * ostride + d * 16 + fm] = f2bf(oacc[tt][d][r] * inv);
        }
    }
}

// ---------------------------------------------------------------------------
extern "C" void kernel_launch(void* const* d_in, const int* in_sizes, int n_in,
                              void* d_out, int out_size, void* d_ws, size_t ws_size,
                              hipStream_t stream) {
    const float* x        = (const float*)d_in[0];
    const float* ctx      = (const float*)d_in[1];
    const float* gn_s     = (const float*)d_in[2];
    const float* gn_b     = (const float*)d_in[3];
    const float* conv1_w  = (const float*)d_in[4];
    const float* conv1_b  = (const float*)d_in[5];
    const float* ln1_s    = (const float*)d_in[6];
    const float* ln1_b    = (const float*)d_in[7];
    const float* sa_in_w  = (const float*)d_in[8];
    const float* sa_out_w = (const float*)d_in[9];
    const float* sa_out_b = (const float*)d_in[10];
    const float* ln2_s    = (const float*)d_in[11];
    const float* ln2_b    = (const float*)d_in[12];
    const float* ca_q_w   = (const float*)d_in[13];
    const float* ca_k_w   = (const float*)d_in[14];
    const float* ca_v_w   = (const float*)d_in[15];
    const float* ca_out_w = (const float*)d_in[16];
    const float* ca_out_b = (const float*)d_in[17];
    const float* ln3_s    = (const float*)d_in[18];
    const float* ln3_b    = (const float*)d_in[19];
    const float* lin1_w   = (const float*)d_in[20];
    const float* lin1_b   = (const float*)d_in[21];
    const float* lin2_w   = (const float*)d_in[22];
    const float* lin2_b   = (const float*)d_in[23];
    const float* co_w     = (const float*)d_in[24];
    const float* co_b     = (const float*)d_in[25];

    float* out = (float*)d_out;
    float* ws = (float*)d_ws;

    // ws layout (float offsets). Only overlay: vT_s shares h_b's first part
    // (vT_s live in step 3 only; h_b written in step 5 only).
    unsigned short* qk_b   = (unsigned short*)ws;               // [8192][1280]
    unsigned short* h_b    = (unsigned short*)(ws + 5242880);   // [8192][2560]
    unsigned short* vT_s   = (unsigned short*)(ws + 5242880);   // [5120][1024] (overlay)
    unsigned short* abuf   = (unsigned short*)(ws + 15728640);  // [8192][640]
    unsigned short* kv0    = (unsigned short*)(ws + 18350080);  // [640][640]
    unsigned short* vT_c   = (unsigned short*)(ws + 18554880);  // [5120][128]
    unsigned short* ctx_b  = (unsigned short*)(ws + 18882560);  // [640][512]
    unsigned short* x_seqb = (unsigned short*)(ws + 19046400);  // [8192][640] bf16 residual
    size_t woff = 21667840;
    unsigned short* sa_in_wb  = (unsigned short*)(ws + woff); woff += 614400;
    unsigned short* sa_out_wb = (unsigned short*)(ws + woff); woff += 204800;
    unsigned short* ca_q_wb   = (unsigned short*)(ws + woff); woff += 204800;
    unsigned short* ca_k_wb   = (unsigned short*)(ws + woff); woff += 163840;
    unsigned short* ca_v_wb   = (unsigned short*)(ws + woff); woff += 163840;
    unsigned short* ca_out_wb = (unsigned short*)(ws + woff); woff += 204800;
    unsigned short* lin1_wb   = (unsigned short*)(ws + woff); woff += 1638400;
    unsigned short* lin2_wb   = (unsigned short*)(ws + woff); woff += 819200;
    unsigned short* conv1_wb  = (unsigned short*)(ws + woff); woff += 204800;
    unsigned short* co_wb     = (unsigned short*)(ws + woff); woff += 204800;
    float* stats = ws + woff;

    const float scale = 0.11180339887498949f;  // 1/sqrt(80)

    // ---- weight prep: 2 launches (R7-proven) ----
    prep_tr_k<<<7840, 256, 0, stream>>>(sa_in_w, sa_in_wb, sa_out_w, sa_out_wb,
                                        ca_q_w, ca_q_wb, ca_k_w, ca_k_wb,
                                        ca_v_w, ca_v_wb, ca_out_w, ca_out_wb,
                                        lin1_w, lin1_wb, lin2_w, lin2_wb);
    prep_ew_k<<<5760, 256, 0, stream>>>(conv1_w, conv1_wb, co_w, co_wb, ctx, ctx_b,
                                        (unsigned int*)vT_c);

    // ---- 1. GroupNorm + transpose (bf16) ----
    gn_stats_k<<<256, 256, 0, stream>>>(x, stats);
    gn_apply_t_k<<<dim3(32, 20, 8), 256, 0, stream>>>(x, stats, gn_s, gn_b, abuf);
    // ---- 2. conv1 -> x_seqb (bf16 residual stream) ----
    bgemm_k<EPI_OUT, unsigned short, 64><<<dim3(128, 5), 256, 0, stream>>>(abuf, 640, conv1_wb, 640, conv1_b, x_seqb, 640, nullptr, nullptr, 8192, 640, 640);
    // ---- 3. LN1 + QKV(+V^T) + self-attn + out-proj (+res) ----
    ln_k<<<2048, 256, 0, stream>>>(x_seqb, ln1_s, ln1_b, abuf);
    bgemm_k<EPI_QKV, unsigned short, 128><<<dim3(64, 15), 256, 0, stream>>>(abuf, 640, sa_in_wb, 640, nullptr, qk_b, 1280, nullptr, vT_s, 8192, 1920, 640);
    mattn_k<<<dim3(8, 8, 8), 256, 0, stream>>>(qk_b, 1280, qk_b + 640, 1280, vT_s, 1024, abuf, 640, 1024, 1024, scale);
    bgemm_k<EPI_RES, unsigned short, 64><<<dim3(128, 5), 256, 0, stream>>>(abuf, 640, sa_out_wb, 640, sa_out_b, x_seqb, 640, nullptr, nullptr, 8192, 640, 640);
    // ---- 4. LN2 + cross-attn (+res) ----
    ln_k<<<2048, 256, 0, stream>>>(x_seqb, ln2_s, ln2_b, abuf);
    cross_gemms_k<<<370, 256, 0, stream>>>(abuf, ctx_b, ca_q_wb, ca_k_wb, ca_v_wb,
                                           qk_b, kv0, vT_c);
    mattn_k<<<dim3(8, 8, 8), 256, 0, stream>>>(qk_b, 640, kv0, 640, vT_c, 128, abuf, 640, 1024, 77, scale);
    bgemm_k<EPI_RES, unsigned short, 64><<<dim3(128, 5), 256, 0, stream>>>(abuf, 640, ca_out_wb, 640, ca_out_b, x_seqb, 640, nullptr, nullptr, 8192, 640, 640);
    // ---- 5. LN3 + fused GeGLU FFN (+res) ----
    ln_k<<<2048, 256, 0, stream>>>(x_seqb, ln3_s, ln3_b, abuf);
    geglu_k<<<dim3(64, 40), 256, 0, stream>>>(abuf, lin1_wb, lin1_wb + (size_t)2560 * 640, lin1_b, h_b);
    bgemm_k<EPI_RES, unsigned short, 64><<<dim3(128, 5), 256, 0, stream>>>(h_b, 2560, lin2_wb, 2560, lin2_b, x_seqb, 640, nullptr, nullptr, 8192, 640, 2560);
    // ---- 6. final conv1x1 + long residual (transposed write, fp32 out) ----
    bgemm_k<EPI_CONVT, float, 64><<<dim3(128, 5), 256, 0, stream>>>(x_seqb, 640, co_wb, 640, co_b, out, 0, x, nullptr, 8192, 640, 640);
}

// Round 12
// 532.147 us; speedup vs baseline: 1.0015x; 1.0015x over previous
//
#include <hip/hip_runtime.h>

// ---------------------------------------------------------------------------
// AttentionBlock (SD-style). Round 12:
//  - BK=64 K-loop for bgemm_k and geglu_k, stored as TWO consecutive BK=32
//    sub-tiles (identical staging pattern / bank behavior; halves the number
//    of vmcnt(0)+barrier drain events — the m97-structure ~20% stall).
//    LDS: MT=128 & geglu 32 KB (3 blocks/CU = 96 KB), MT=64 24 KB (4 = 96 KB)
//    -> occupancy preserved (avoids m132's BK=128 occupancy regression).
//  - Everything else identical to R11 (533 µs): bf16 residual, S^T mattn,
//    launch_bounds hints, separate preps.
// B=8, C=640, HW=1024, H=8, DH=80, CTX 77x512.
// ---------------------------------------------------------------------------

#define DH 80

typedef __attribute__((ext_vector_type(8))) short bf16x8;
typedef __attribute__((ext_vector_type(4))) float floatx4;

static __device__ __forceinline__ float gelu_f(float x) {
    return 0.5f * x * (1.0f + erff(x * 0.70710678118654752f));
}
static __device__ __forceinline__ unsigned short f2bf(float f) {
    unsigned u = __float_as_uint(f);
    u = (u + 0x7fffu + ((u >> 16) & 1u)) >> 16;
    return (unsigned short)u;
}
static __device__ __forceinline__ float bf2f(unsigned short s) {
    return __uint_as_float(((unsigned)s) << 16);
}
static __device__ __forceinline__ void async_copy16(const void* g, void* l) {
    __builtin_amdgcn_global_load_lds(
        (const __attribute__((address_space(1))) unsigned int*)g,
        (__attribute__((address_space(3))) unsigned int*)l, 16, 0, 0);
}

// ------------------------- GroupNorm stats ---------------------------------
__global__ __launch_bounds__(256) void gn_stats_k(const float* __restrict__ x,
                                                  float* __restrict__ stats) {
    const int ng = blockIdx.x;                       // n*32 + g
    const float4* base = (const float4*)(x + (size_t)ng * 20480);
    float s = 0.f, s2 = 0.f;
    for (int i = threadIdx.x; i < 5120; i += 256) {
        float4 v = base[i];
        s  += v.x + v.y + v.z + v.w;
        s2 += v.x*v.x + v.y*v.y + v.z*v.z + v.w*v.w;
    }
    for (int m = 1; m < 64; m <<= 1) { s += __shfl_xor(s, m); s2 += __shfl_xor(s2, m); }
    __shared__ float rs[4], rs2[4];
    if ((threadIdx.x & 63) == 0) { rs[threadIdx.x >> 6] = s; rs2[threadIdx.x >> 6] = s2; }
    __syncthreads();
    if (threadIdx.x == 0) {
        float ts = rs[0] + rs[1] + rs[2] + rs[3];
        float t2 = rs2[0] + rs2[1] + rs2[2] + rs2[3];
        float mu = ts * (1.f / 20480.f);
        float var = t2 * (1.f / 20480.f) - mu * mu;
        stats[ng * 2]     = mu;
        stats[ng * 2 + 1] = rsqrtf(var + 1e-6f);
    }
}

// ----------------- GroupNorm apply + transpose, bf16 out --------------------
__global__ __launch_bounds__(256) void gn_apply_t_k(const float* __restrict__ x,
                                                    const float* __restrict__ stats,
                                                    const float* __restrict__ gs,
                                                    const float* __restrict__ gb,
                                                    unsigned short* __restrict__ out) {
    const int p0 = blockIdx.x * 32, c0 = blockIdx.y * 32, n = blockIdx.z;
    __shared__ float tile[32][33];
    const int t = threadIdx.x;
    {
        const int cl = t >> 5, pl = t & 31;
#pragma unroll
        for (int i = 0; i < 4; ++i) {
            int c = c0 + cl + i * 8;
            int g = c / 20;
            float mu = stats[(n * 32 + g) * 2];
            float rstd = stats[(n * 32 + g) * 2 + 1];
            float v = x[(size_t)n * 655360 + (size_t)c * 1024 + p0 + pl];
            tile[cl + i * 8][pl] = (v - mu) * rstd * gs[c] + gb[c];
        }
    }
    __syncthreads();
    {
        const int pl = t >> 5, cl = t & 31;
#pragma unroll
        for (int i = 0; i < 4; ++i) {
            int p = p0 + pl + i * 8;
            out[((size_t)n * 1024 + p) * 640 + c0 + cl] = f2bf(tile[cl][pl + i * 8]);
        }
    }
}

// --------------------- LayerNorm (bf16 in, bf16 out) ------------------------
__global__ __launch_bounds__(256) void ln_k(const unsigned short* __restrict__ x,
                                            const float* __restrict__ g,
                                            const float* __restrict__ b,
                                            unsigned short* __restrict__ o) {
    const int row = blockIdx.x * 4 + (threadIdx.x >> 6);
    const int lane = threadIdx.x & 63;
    const unsigned short* xr = x + (size_t)row * 640;
    float v[10];
    float s = 0.f, s2 = 0.f;
#pragma unroll
    for (int i = 0; i < 10; ++i) {
        v[i] = bf2f(xr[lane + i * 64]);
        s += v[i]; s2 += v[i] * v[i];
    }
    for (int m = 1; m < 64; m <<= 1) { s += __shfl_xor(s, m); s2 += __shfl_xor(s2, m); }
    float mu = s * (1.f / 640.f);
    float var = s2 * (1.f / 640.f) - mu * mu;
    float r = rsqrtf(var + 1e-5f);
    unsigned short* orow = o + (size_t)row * 640;
#pragma unroll
    for (int i = 0; i < 10; ++i) {
        int c = lane + i * 64;
        orow[c] = f2bf((v[i] - mu) * r * g[c] + b[c]);
    }
}

// ---------------- merged weight prep: all [K][N]->[N][K] transposes ---------
__global__ __launch_bounds__(256) void prep_tr_k(
        const float* __restrict__ sa_in_w,  unsigned short* __restrict__ sa_in_wb,
        const float* __restrict__ sa_out_w, unsigned short* __restrict__ sa_out_wb,
        const float* __restrict__ ca_q_w,   unsigned short* __restrict__ ca_q_wb,
        const float* __restrict__ ca_k_w,   unsigned short* __restrict__ ca_k_wb,
        const float* __restrict__ ca_v_w,   unsigned short* __restrict__ ca_v_wb,
        const float* __restrict__ ca_out_w, unsigned short* __restrict__ ca_out_wb,
        const float* __restrict__ lin1_w,   unsigned short* __restrict__ lin1_wb,
        const float* __restrict__ lin2_w,   unsigned short* __restrict__ lin2_wb) {
    const int bid = blockIdx.x;
    int r; const float* W; unsigned short* O; int K, N;
    if (bid < 1200)      { r = bid;        W = sa_in_w;  O = sa_in_wb;  K = 640;  N = 1920; }
    else if (bid < 1600) { r = bid - 1200; W = sa_out_w; O = sa_out_wb; K = 640;  N = 640;  }
    else if (bid < 2000) { r = bid - 1600; W = ca_q_w;   O = ca_q_wb;   K = 640;  N = 640;  }
    else if (bid < 2320) { r = bid - 2000; W = ca_k_w;   O = ca_k_wb;   K = 512;  N = 640;  }
    else if (bid < 2640) { r = bid - 2320; W = ca_v_w;   O = ca_v_wb;   K = 512;  N = 640;  }
    else if (bid < 3040) { r = bid - 2640; W = ca_out_w; O = ca_out_wb; K = 640;  N = 640;  }
    else if (bid < 6240) { r = bid - 3040; W = lin1_w;   O = lin1_wb;   K = 640;  N = 5120; }
    else                 { r = bid - 6240; W = lin2_w;   O = lin2_wb;   K = 2560; N = 640;  }
    const int tX = K >> 5;
    const int k0 = (r % tX) * 32, n0 = (r / tX) * 32;
    __shared__ float tile[32][33];
    const int tr = threadIdx.x >> 5, tc = threadIdx.x & 31;
#pragma unroll
    for (int i = 0; i < 4; ++i)
        tile[tr + i * 8][tc] = W[(size_t)(k0 + tr + i * 8) * N + n0 + tc];
    __syncthreads();
#pragma unroll
    for (int i = 0; i < 4; ++i)
        O[(size_t)(n0 + tr + i * 8) * K + k0 + tc] = f2bf(tile[tc][tr + i * 8]);
}

// ------- merged elementwise prep: conv1/co cvt, ctx pad-cvt, zero vT_c ------
__global__ __launch_bounds__(256) void prep_ew_k(const float* __restrict__ w1,
                                                 unsigned short* __restrict__ c1,
                                                 const float* __restrict__ w2,
                                                 unsigned short* __restrict__ c2,
                                                 const float* __restrict__ ctx,
                                                 unsigned short* __restrict__ cb,
                                                 unsigned int* __restrict__ vtc) {
    const int i = blockIdx.x * 256 + threadIdx.x;
    if (i < 409600) c1[i] = f2bf(w1[i]);
    else if (i < 819200) c2[i - 409600] = f2bf(w2[i - 409600]);
    else if (i < 1146880) {
        const int j = i - 819200;
        const int r = j >> 9;
        cb[j] = (r < 616) ? f2bf(ctx[j]) : (unsigned short)0;
    } else {
        vtc[i - 1146880] = 0u;   // zero cross V^T (masked cols read by attn)
    }
}

// --------------------------- bf16 MFMA GEMM ---------------------------------
// C[M,N] = A[M,K] * B^T[N,K] (+bias, epilogue). MT in {128, 64}.
// BK=64 as two consecutive BK=32 sub-tiles (half the barriers, same staging).
enum { EPI_OUT = 0, EPI_RES = 1, EPI_CONVT = 3, EPI_QKV = 5 };

template <int EPI, typename CT, int MT>
__global__ __launch_bounds__(256, MT == 128 ? 3 : 4)
void bgemm_k(const unsigned short* __restrict__ A, int lda,
             const unsigned short* __restrict__ B, int ldb,
             const float* __restrict__ bias,
             CT* __restrict__ C, int ldc,
             const float* __restrict__ aux,
             unsigned short* __restrict__ extra,
             int M, int N, int K) {
    constexpr int MI = MT / 32;   // m-fragments per wave (4 or 2)
    __shared__ __attribute__((aligned(16))) short As[2 * MT * 32];
    __shared__ __attribute__((aligned(16))) short Bs[2 * 128 * 32];
    const int t = threadIdx.x;
    const int lane = t & 63;
    const int w = __builtin_amdgcn_readfirstlane(t >> 6);
    const int m0 = blockIdx.x * MT, n0 = blockIdx.y * 128;
    const int wm = (MT == 128) ? (w >> 1) * 64 : (w & 1) * 32;
    const int wn = (MT == 128) ? (w & 1) * 64 : (w >> 1) * 64;

    const int sr = lane >> 2;
    const int sc = (lane & 3) * 8;
    const int fm = lane & 15;
    const int fq = (lane >> 4) * 8;

    floatx4 acc[MI][4];
#pragma unroll
    for (int i = 0; i < MI; ++i)
#pragma unroll
        for (int j = 0; j < 4; ++j) acc[i][j] = (floatx4){0.f, 0.f, 0.f, 0.f};

    for (int k0 = 0; k0 < K; k0 += 64) {
#pragma unroll
        for (int s = 0; s < 2; ++s) {
            const unsigned short* a0 = A + (size_t)(m0 + w * 16 + sr) * lda + k0 + s * 32 + sc;
            const unsigned short* b0 = B + (size_t)(n0 + w * 16 + sr) * ldb + k0 + s * 32 + sc;
            async_copy16(a0, As + s * (MT * 32) + (w * 16) * 32);
            if constexpr (MT == 128)
                async_copy16(a0 + (size_t)64 * lda, As + s * (MT * 32) + (64 + w * 16) * 32);
            async_copy16(b0,                    Bs + s * 4096 + (w * 16) * 32);
            async_copy16(b0 + (size_t)64 * ldb, Bs + s * 4096 + (64 + w * 16) * 32);
        }
        __syncthreads();
#pragma unroll
        for (int s = 0; s < 2; ++s) {
            bf16x8 af[MI], bfr[4];
#pragma unroll
            for (int i = 0; i < MI; ++i)
                af[i]  = *(const bf16x8*)(As + s * (MT * 32) + (wm + i * 16 + fm) * 32 + fq);
#pragma unroll
            for (int j = 0; j < 4; ++j)
                bfr[j] = *(const bf16x8*)(Bs + s * 4096 + (wn + j * 16 + fm) * 32 + fq);
#pragma unroll
            for (int i = 0; i < MI; ++i)
#pragma unroll
                for (int j = 0; j < 4; ++j)
                    acc[i][j] = __builtin_amdgcn_mfma_f32_16x16x32_bf16(af[i], bfr[j], acc[i][j], 0, 0, 0);
        }
        __syncthreads();
    }

    float bv[4];
#pragma unroll
    for (int j = 0; j < 4; ++j) bv[j] = bias ? bias[n0 + wn + j * 16 + fm] : 0.f;
    const int rbase = (lane >> 4) * 4;

#pragma unroll
    for (int i = 0; i < MI; ++i) {
#pragma unroll
        for (int j = 0; j < 4; ++j) {
            const int n = n0 + wn + j * 16 + fm;
#pragma unroll
            for (int r = 0; r < 4; ++r) {
                const int m = m0 + wm + i * 16 + rbase + r;
                float v = acc[i][j][r] + bv[j];
                if constexpr (EPI == EPI_OUT) {
                    if constexpr (__is_same(CT, float)) {
                        C[(size_t)m * ldc + n] = v;
                    } else {
                        C[(size_t)m * ldc + n] = f2bf(v);
                    }
                } else if constexpr (EPI == EPI_RES) {
                    const size_t idx = (size_t)m * ldc + n;
                    if constexpr (__is_same(CT, float)) {
                        C[idx] += v;
                    } else {
                        C[idx] = f2bf(bf2f(C[idx]) + v);  // bf16 residual RMW
                    }
                } else if constexpr (EPI == EPI_CONVT) {
                    const int bch = m >> 10, p = m & 1023;
                    const size_t idx = (size_t)bch * 655360 + (size_t)n * 1024 + p;
                    C[idx] = v + aux[idx];
                } else {  // EPI_QKV: n<1280 -> qk store; else V^T scatter
                    if (n < 1280) {
                        C[(size_t)m * 1280 + n] = f2bf(v);
                    } else {
                        const int nv2 = n - 1280;
                        const int hh = nv2 / 80, d = nv2 - hh * 80;
                        const int bb = m >> 10, s = m & 1023;
                        extra[((size_t)(bb * 8 + hh) * 80 + d) * 1024 + s] = f2bf(v);
                    }
                }
            }
        }
    }
}

// -------- cross-attn projections: q (8192x640) + K,V (640x640) in one -------
__global__ __launch_bounds__(256, 2) void cross_gemms_k(
        const unsigned short* __restrict__ xq, const unsigned short* __restrict__ ctx_b,
        const unsigned short* __restrict__ Wq, const unsigned short* __restrict__ Wk,
        const unsigned short* __restrict__ Wv,
        unsigned short* __restrict__ q_out, unsigned short* __restrict__ k_out,
        unsigned short* __restrict__ vT_out) {
    __shared__ __attribute__((aligned(16))) short As[128 * 32];
    __shared__ __attribute__((aligned(16))) short Bs[128 * 32];
    const int bx = blockIdx.x;
    int job, m0, n0, lda, K;
    const unsigned short *A, *B;
    if (bx < 320)      { job = 0; m0 = (bx & 63) * 128; n0 = (bx >> 6) * 128; A = xq;    B = Wq; lda = 640; K = 640; }
    else if (bx < 345) { int i = bx - 320; job = 1; m0 = (i % 5) * 128; n0 = (i / 5) * 128; A = ctx_b; B = Wk; lda = 512; K = 512; }
    else               { int i = bx - 345; job = 2; m0 = (i % 5) * 128; n0 = (i / 5) * 128; A = ctx_b; B = Wv; lda = 512; K = 512; }

    const int t = threadIdx.x;
    const int lane = t & 63;
    const int w = __builtin_amdgcn_readfirstlane(t >> 6);
    const int wm = (w >> 1) * 64, wn = (w & 1) * 64;
    const int sr = lane >> 2, sc = (lane & 3) * 8;
    const int fm = lane & 15, fq = (lane >> 4) * 8;

    floatx4 acc[4][4];
#pragma unroll
    for (int i = 0; i < 4; ++i)
#pragma unroll
        for (int j = 0; j < 4; ++j) acc[i][j] = (floatx4){0.f, 0.f, 0.f, 0.f};

    for (int k0 = 0; k0 < K; k0 += 32) {
        const unsigned short* a0 = A + (size_t)(m0 + w * 16 + sr) * lda + k0 + sc;
        const unsigned short* b0 = B + (size_t)(n0 + w * 16 + sr) * lda + k0 + sc;
        async_copy16(a0,                    As + (w * 16) * 32);
        async_copy16(a0 + (size_t)64 * lda, As + (64 + w * 16) * 32);
        async_copy16(b0,                    Bs + (w * 16) * 32);
        async_copy16(b0 + (size_t)64 * lda, Bs + (64 + w * 16) * 32);
        __syncthreads();
        bf16x8 af[4], bfr[4];
#pragma unroll
        for (int i = 0; i < 4; ++i) {
            af[i]  = *(const bf16x8*)(As + (wm + i * 16 + fm) * 32 + fq);
            bfr[i] = *(const bf16x8*)(Bs + (wn + i * 16 + fm) * 32 + fq);
        }
#pragma unroll
        for (int i = 0; i < 4; ++i)
#pragma unroll
            for (int j = 0; j < 4; ++j)
                acc[i][j] = __builtin_amdgcn_mfma_f32_16x16x32_bf16(af[i], bfr[j], acc[i][j], 0, 0, 0);
        __syncthreads();
    }

    const int rbase = (lane >> 4) * 4;
#pragma unroll
    for (int i = 0; i < 4; ++i) {
#pragma unroll
        for (int j = 0; j < 4; ++j) {
            const int n = n0 + wn + j * 16 + fm;
#pragma unroll
            for (int r = 0; r < 4; ++r) {
                const int m = m0 + wm + i * 16 + rbase + r;
                const float v = acc[i][j][r];
                if (job == 0) {
                    q_out[(size_t)m * 640 + n] = f2bf(v);
                } else if (job == 1) {
                    k_out[(size_t)m * 640 + n] = f2bf(v);
                } else {
                    if (m < 616) {
                        const int bb = m / 77, s = m - bb * 77;
                        const int hh = n / 80, d = n - hh * 80;
                        vT_out[((size_t)(bb * 8 + hh) * 80 + d) * 128 + s] = f2bf(v);
                    }
                }
            }
        }
    }
}

// ---------------- fused GeGLU lin1: h = a * gelu(gate), dual-B GEMM ---------
// 128-M x 64-N dual tile; BK=64 (two BK=32 sub-tiles); LDS 32 KB; 3 blocks/CU.
__global__ __launch_bounds__(256, 3) void geglu_k(const unsigned short* __restrict__ A,
                                                  const unsigned short* __restrict__ B1,
                                                  const unsigned short* __restrict__ B2,
                                                  const float* __restrict__ bias,  // [5120]
                                                  unsigned short* __restrict__ H) {
    __shared__ __attribute__((aligned(16))) short As[2 * 128 * 32];
    __shared__ __attribute__((aligned(16))) short B1s[2 * 64 * 32];
    __shared__ __attribute__((aligned(16))) short B2s[2 * 64 * 32];
    const int t = threadIdx.x;
    const int lane = t & 63;
    const int w = __builtin_amdgcn_readfirstlane(t >> 6);
    const int m0 = blockIdx.x * 128, n0 = blockIdx.y * 64;
    const int wm = (w & 1) * 64, wn = (w >> 1) * 32;
    const int sr = lane >> 2, sc = (lane & 3) * 8;
    const int fm = lane & 15, fq = (lane >> 4) * 8;

    floatx4 aa[4][2], ag[4][2];
#pragma unroll
    for (int i = 0; i < 4; ++i)
#pragma unroll
        for (int j = 0; j < 2; ++j) {
            aa[i][j] = (floatx4){0.f, 0.f, 0.f, 0.f};
            ag[i][j] = (floatx4){0.f, 0.f, 0.f, 0.f};
        }

    for (int k0 = 0; k0 < 640; k0 += 64) {
#pragma unroll
        for (int s = 0; s < 2; ++s) {
            const unsigned short* a0 = A  + (size_t)(m0 + w * 16 + sr) * 640 + k0 + s * 32 + sc;
            const unsigned short* b1 = B1 + (size_t)(n0 + w * 16 + sr) * 640 + k0 + s * 32 + sc;
            const unsigned short* b2 = B2 + (size_t)(n0 + w * 16 + sr) * 640 + k0 + s * 32 + sc;
            async_copy16(a0,                    As  + s * 4096 + (w * 16) * 32);
            async_copy16(a0 + (size_t)64 * 640, As  + s * 4096 + (64 + w * 16) * 32);
            async_copy16(b1,                    B1s + s * 2048 + (w * 16) * 32);
            async_copy16(b2,                    B2s + s * 2048 + (w * 16) * 32);
        }
        __syncthreads();
#pragma unroll
        for (int s = 0; s < 2; ++s) {
            bf16x8 af[4], b1f[2], b2f[2];
#pragma unroll
            for (int i = 0; i < 4; ++i)
                af[i]  = *(const bf16x8*)(As  + s * 4096 + (wm + i * 16 + fm) * 32 + fq);
#pragma unroll
            for (int j = 0; j < 2; ++j) {
                b1f[j] = *(const bf16x8*)(B1s + s * 2048 + (wn + j * 16 + fm) * 32 + fq);
                b2f[j] = *(const bf16x8*)(B2s + s * 2048 + (wn + j * 16 + fm) * 32 + fq);
            }
#pragma unroll
            for (int i = 0; i < 4; ++i)
#pragma unroll
                for (int j = 0; j < 2; ++j) {
                    aa[i][j] = __builtin_amdgcn_mfma_f32_16x16x32_bf16(af[i], b1f[j], aa[i][j], 0, 0, 0);
                    ag[i][j] = __builtin_amdgcn_mfma_f32_16x16x32_bf16(af[i], b2f[j], ag[i][j], 0, 0, 0);
                }
        }
        __syncthreads();
    }

    float bv1[2], bv2[2];
#pragma unroll
    for (int j = 0; j < 2; ++j) {
        bv1[j] = bias[n0 + wn + j * 16 + fm];
        bv2[j] = bias[2560 + n0 + wn + j * 16 + fm];
    }
    const int rbase = (lane >> 4) * 4;
#pragma unroll
    for (int i = 0; i < 4; ++i)
#pragma unroll
        for (int j = 0; j < 2; ++j) {
            const int n = n0 + wn + j * 16 + fm;
#pragma unroll
            for (int r = 0; r < 4; ++r) {
                const int m = m0 + wm + i * 16 + rbase + r;
                const float a = aa[i][j][r] + bv1[j];
                const float g = ag[i][j][r] + bv2[j];
                H[(size_t)m * 2560 + n] = f2bf(a * gelu_f(g));
            }
        }
}

// -------------------- MFMA flash attention (S^T, 2 q-tiles/wave) ------------
__global__ __launch_bounds__(256, 3) void mattn_k(const unsigned short* __restrict__ Qp, int qstride,
                                                  const unsigned short* __restrict__ Kp, int kstride,
                                                  const unsigned short* __restrict__ Vt, int spad,
                                                  unsigned short* __restrict__ Op, int ostride,
                                                  int sq, int sk, float scale) {
    __shared__ __attribute__((aligned(16))) short Ks[64 * 104];   // [64 k][96+8]
    __shared__ __attribute__((aligned(16))) short Vs[80 * 72];    // [80 d][64+8]
    __shared__ __attribute__((aligned(16))) short Ps[128 * 72];   // [128 q][64+8]

    const int t = threadIdx.x;
    const int lane = t & 63;
    const int w = t >> 6;
    const int fm = lane & 15;
    const int quad = lane >> 4;
    const int b = blockIdx.z, h = blockIdx.y;
    const int q0 = blockIdx.x * 128;
    const int qw = q0 + w * 32;            // wave's first q row

    const bf16x8 z8 = {0, 0, 0, 0, 0, 0, 0, 0};
    bf16x8 qf[2][3];
#pragma unroll
    for (int tt = 0; tt < 2; ++tt) {
        const unsigned short* qbase =
            Qp + (size_t)(b * sq + qw + tt * 16 + fm) * qstride + h * DH;
        qf[tt][0] = *(const bf16x8*)(qbase + quad * 8);
        qf[tt][1] = *(const bf16x8*)(qbase + 32 + quad * 8);
        qf[tt][2] = (quad < 2) ? *(const bf16x8*)(qbase + 64 + quad * 8) : z8;
    }

    const unsigned short* kgb = Kp + (size_t)(b * sk) * kstride + h * DH;
    const unsigned short* vgb = Vt + (size_t)((b * 8 + h) * 80) * spad;

    float mrow[2] = {-1e30f, -1e30f}, lrow[2] = {0.f, 0.f};
    floatx4 oacc[2][5];
#pragma unroll
    for (int tt = 0; tt < 2; ++tt)
#pragma unroll
        for (int d = 0; d < 5; ++d) oacc[tt][d] = (floatx4){0.f, 0.f, 0.f, 0.f};

    const int nkt = (sk + 63) >> 6;
    for (int kt = 0; kt < nkt; ++kt) {
        __syncthreads();
        {
            const int tr = t >> 2, tc = t & 3;
            const int kr = kt * 64 + tr;
            const bool ok = kr < sk;
            const unsigned short* krow = kgb + (size_t)kr * kstride;
#pragma unroll
            for (int i = 0; i < 5; ++i) {
                const int col = tc * 4 + i * 16;
                ushort4 v = make_ushort4(0, 0, 0, 0);
                if (ok) v = *(const ushort4*)(krow + col);
                *(ushort4*)(Ks + tr * 104 + col) = v;
            }
            *(ushort4*)(Ks + tr * 104 + 80 + tc * 4) = make_ushort4(0, 0, 0, 0);
        }
#pragma unroll
        for (int i = 0; i < 5; ++i) {
            const int lin = t + i * 256;
            const int row = lin >> 4;
            const int colq = (lin & 15) * 4;
            *(ushort4*)(Vs + row * 72 + colq) =
                *(const ushort4*)(vgb + (size_t)row * spad + kt * 64 + colq);
        }
        __syncthreads();

        floatx4 sacc[2][4];
#pragma unroll
        for (int tt = 0; tt < 2; ++tt)
#pragma unroll
            for (int j = 0; j < 4; ++j) sacc[tt][j] = (floatx4){0.f, 0.f, 0.f, 0.f};
#pragma unroll
        for (int c = 0; c < 3; ++c) {
#pragma unroll
            for (int j = 0; j < 4; ++j) {
                bf16x8 kf = *(const bf16x8*)(Ks + (j * 16 + fm) * 104 + c * 32 + quad * 8);
                sacc[0][j] = __builtin_amdgcn_mfma_f32_16x16x32_bf16(kf, qf[0][c], sacc[0][j], 0, 0, 0);
                sacc[1][j] = __builtin_amdgcn_mfma_f32_16x16x32_bf16(kf, qf[1][c], sacc[1][j], 0, 0, 0);
            }
        }

#pragma unroll
        for (int tt = 0; tt < 2; ++tt) {
            float p[4][4];
#pragma unroll
            for (int j = 0; j < 4; ++j)
#pragma unroll
                for (int r = 0; r < 4; ++r) {
                    const int kk = kt * 64 + j * 16 + quad * 4 + r;
                    p[j][r] = (kk >= sk) ? -1e30f : sacc[tt][j][r] * scale;
                }
            float mx = p[0][0];
#pragma unroll
            for (int j = 0; j < 4; ++j)
#pragma unroll
                for (int r = 0; r < 4; ++r) mx = fmaxf(mx, p[j][r]);
            mx = fmaxf(mx, __shfl_xor(mx, 16));
            mx = fmaxf(mx, __shfl_xor(mx, 32));
            const float mn = fmaxf(mrow[tt], mx);
            const float alpha = __expf(mrow[tt] - mn);
            float rs = 0.f;
#pragma unroll
            for (int j = 0; j < 4; ++j)
#pragma unroll
                for (int r = 0; r < 4; ++r) { p[j][r] = __expf(p[j][r] - mn); rs += p[j][r]; }
            rs += __shfl_xor(rs, 16);
            rs += __shfl_xor(rs, 32);
            lrow[tt] = lrow[tt] * alpha + rs;
            mrow[tt] = mn;

            float al[4];
#pragma unroll
            for (int r = 0; r < 4; ++r) al[r] = __shfl(alpha, quad * 4 + r);
#pragma unroll
            for (int d = 0; d < 5; ++d)
#pragma unroll
                for (int r = 0; r < 4; ++r) oacc[tt][d][r] *= al[r];

#pragma unroll
            for (int j = 0; j < 4; ++j) {
                ushort4 pk;
                pk.x = f2bf(p[j][0]); pk.y = f2bf(p[j][1]);
                pk.z = f2bf(p[j][2]); pk.w = f2bf(p[j][3]);
                *(ushort4*)(Ps + (w * 32 + tt * 16 + fm) * 72 + j * 16 + quad * 4) = pk;
            }
        }
        __syncthreads();

        bf16x8 pf[2][2];
#pragma unroll
        for (int tt = 0; tt < 2; ++tt) {
            pf[tt][0] = *(const bf16x8*)(Ps + (w * 32 + tt * 16 + fm) * 72 + quad * 8);
            pf[tt][1] = *(const bf16x8*)(Ps + (w * 32 + tt * 16 + fm) * 72 + 32 + quad * 8);
        }
#pragma unroll
        for (int d = 0; d < 5; ++d) {
            bf16x8 vf0 = *(const bf16x8*)(Vs + (d * 16 + fm) * 72 + quad * 8);
            bf16x8 vf1 = *(const bf16x8*)(Vs + (d * 16 + fm) * 72 + 32 + quad * 8);
#pragma unroll
            for (int tt = 0; tt < 2; ++tt) {
                oacc[tt][d] = __builtin_amdgcn_mfma_f32_16x16x32_bf16(pf[tt][0], vf0, oacc[tt][d], 0, 0, 0);
                oacc[tt][d] = __builtin_amdgcn_mfma_f32_16x16x32_bf16(pf[tt][1], vf1, oacc[tt][d], 0, 0, 0);
            }
        }
    }

#pragma unroll
    for (int tt = 0; tt < 2; ++tt) {
        unsigned short* obase = Op + (size_t)(b * sq + qw + tt * 16) * ostride + h * DH;
#pragma unroll
        for (int r = 0; r < 4; ++r) {
            const float lr = __shfl(lrow[tt], quad * 4 + r);
            const float inv = 1.f / lr;
#pragma unroll
            for (int d = 0; d < 5; ++d)
                obase[(size_t)(quad * 4 + r) * ostride + d * 16 + fm] = f2bf(oacc[tt][d][r] * inv);
        }
    }
}

// ---------------------------------------------------------------------------
extern "C" void kernel_launch(void* const* d_in, const int* in_sizes, int n_in,
                              void* d_out, int out_size, void* d_ws, size_t ws_size,
                              hipStream_t stream) {
    const float* x        = (const float*)d_in[0];
    const float* ctx      = (const float*)d_in[1];
    const float* gn_s     = (const float*)d_in[2];
    const float* gn_b     = (const float*)d_in[3];
    const float* conv1_w  = (const float*)d_in[4];
    const float* conv1_b  = (const float*)d_in[5];
    const float* ln1_s    = (const float*)d_in[6];
    const float* ln1_b    = (const float*)d_in[7];
    const float* sa_in_w  = (const float*)d_in[8];
    const float* sa_out_w = (const float*)d_in[9];
    const float* sa_out_b = (const float*)d_in[10];
    const float* ln2_s    = (const float*)d_in[11];
    const float* ln2_b    = (const float*)d_in[12];
    const float* ca_q_w   = (const float*)d_in[13];
    const float* ca_k_w   = (const float*)d_in[14];
    const float* ca_v_w   = (const float*)d_in[15];
    const float* ca_out_w = (const float*)d_in[16];
    const float* ca_out_b = (const float*)d_in[17];
    const float* ln3_s    = (const float*)d_in[18];
    const float* ln3_b    = (const float*)d_in[19];
    const float* lin1_w   = (const float*)d_in[20];
    const float* lin1_b   = (const float*)d_in[21];
    const float* lin2_w   = (const float*)d_in[22];
    const float* lin2_b   = (const float*)d_in[23];
    const float* co_w     = (const float*)d_in[24];
    const float* co_b     = (const float*)d_in[25];

    float* out = (float*)d_out;
    float* ws = (float*)d_ws;

    // ws layout (float offsets). Only overlay: vT_s shares h_b's first part
    // (vT_s live in step 3 only; h_b written in step 5 only).
    unsigned short* qk_b   = (unsigned short*)ws;               // [8192][1280]
    unsigned short* h_b    = (unsigned short*)(ws + 5242880);   // [8192][2560]
    unsigned short* vT_s   = (unsigned short*)(ws + 5242880);   // [5120][1024] (overlay)
    unsigned short* abuf   = (unsigned short*)(ws + 15728640);  // [8192][640]
    unsigned short* kv0    = (unsigned short*)(ws + 18350080);  // [640][640]
    unsigned short* vT_c   = (unsigned short*)(ws + 18554880);  // [5120][128]
    unsigned short* ctx_b  = (unsigned short*)(ws + 18882560);  // [640][512]
    unsigned short* x_seqb = (unsigned short*)(ws + 19046400);  // [8192][640] bf16 residual
    size_t woff = 21667840;
    unsigned short* sa_in_wb  = (unsigned short*)(ws + woff); woff += 614400;
    unsigned short* sa_out_wb = (unsigned short*)(ws + woff); woff += 204800;
    unsigned short* ca_q_wb   = (unsigned short*)(ws + woff); woff += 204800;
    unsigned short* ca_k_wb   = (unsigned short*)(ws + woff); woff += 163840;
    unsigned short* ca_v_wb   = (unsigned short*)(ws + woff); woff += 163840;
    unsigned short* ca_out_wb = (unsigned short*)(ws + woff); woff += 204800;
    unsigned short* lin1_wb   = (unsigned short*)(ws + woff); woff += 1638400;
    unsigned short* lin2_wb   = (unsigned short*)(ws + woff); woff += 819200;
    unsigned short* conv1_wb  = (unsigned short*)(ws + woff); woff += 204800;
    unsigned short* co_wb     = (unsigned short*)(ws + woff); woff += 204800;
    float* stats = ws + woff;

    const float scale = 0.11180339887498949f;  // 1/sqrt(80)

    // ---- weight prep: 2 launches (R7-proven) ----
    prep_tr_k<<<7840, 256, 0, stream>>>(sa_in_w, sa_in_wb, sa_out_w, sa_out_wb,
                                        ca_q_w, ca_q_wb, ca_k_w, ca_k_wb,
                                        ca_v_w, ca_v_wb, ca_out_w, ca_out_wb,
                                        lin1_w, lin1_wb, lin2_w, lin2_wb);
    prep_ew_k<<<5760, 256, 0, stream>>>(conv1_w, conv1_wb, co_w, co_wb, ctx, ctx_b,
                                        (unsigned int*)vT_c);

    // ---- 1. GroupNorm + transpose (bf16) ----
    gn_stats_k<<<256, 256, 0, stream>>>(x, stats);
    gn_apply_t_k<<<dim3(32, 20, 8), 256, 0, stream>>>(x, stats, gn_s, gn_b, abuf);
    // ---- 2. conv1 -> x_seqb (bf16 residual stream) ----
    bgemm_k<EPI_OUT, unsigned short, 64><<<dim3(128, 5), 256, 0, stream>>>(abuf, 640, conv1_wb, 640, conv1_b, x_seqb, 640, nullptr, nullptr, 8192, 640, 640);
    // ---- 3. LN1 + QKV(+V^T) + self-attn + out-proj (+res) ----
    ln_k<<<2048, 256, 0, stream>>>(x_seqb, ln1_s, ln1_b, abuf);
    bgemm_k<EPI_QKV, unsigned short, 128><<<dim3(64, 15), 256, 0, stream>>>(abuf, 640, sa_in_wb, 640, nullptr, qk_b, 1280, nullptr, vT_s, 8192, 1920, 640);
    mattn_k<<<dim3(8, 8, 8), 256, 0, stream>>>(qk_b, 1280, qk_b + 640, 1280, vT_s, 1024, abuf, 640, 1024, 1024, scale);
    bgemm_k<EPI_RES, unsigned short, 64><<<dim3(128, 5), 256, 0, stream>>>(abuf, 640, sa_out_wb, 640, sa_out_b, x_seqb, 640, nullptr, nullptr, 8192, 640, 640);
    // ---- 4. LN2 + cross-attn (+res) ----
    ln_k<<<2048, 256, 0, stream>>>(x_seqb, ln2_s, ln2_b, abuf);
    cross_gemms_k<<<370, 256, 0, stream>>>(abuf, ctx_b, ca_q_wb, ca_k_wb, ca_v_wb,
                                           qk_b, kv0, vT_c);
    mattn_k<<<dim3(8, 8, 8), 256, 0, stream>>>(qk_b, 640, kv0, 640, vT_c, 128, abuf, 640, 1024, 77, scale);
    bgemm_k<EPI_RES, unsigned short, 64><<<dim3(128, 5), 256, 0, stream>>>(abuf, 640, ca_out_wb, 640, ca_out_b, x_seqb, 640, nullptr, nullptr, 8192, 640, 640);
    // ---- 5. LN3 + fused GeGLU FFN (+res) ----
    ln_k<<<2048, 256, 0, stream>>>(x_seqb, ln3_s, ln3_b, abuf);
    geglu_k<<<dim3(64, 40), 256, 0, stream>>>(abuf, lin1_wb, lin1_wb + (size_t)2560 * 640, lin1_b, h_b);
    bgemm_k<EPI_RES, unsigned short, 64><<<dim3(128, 5), 256, 0, stream>>>(h_b, 2560, lin2_wb, 2560, lin2_b, x_seqb, 640, nullptr, nullptr, 8192, 640, 2560);
    // ---- 6. final conv1x1 + long residual (transposed write, fp32 out) ----
    bgemm_k<EPI_CONVT, float, 64><<<dim3(128, 5), 256, 0, stream>>>(x_seqb, 640, co_wb, 640, co_b, out, 0, x, nullptr, 8192, 640, 640);
}